// Round 1
// baseline (214.930 us; speedup 1.0000x reference)
//
#include <hip/hip_runtime.h>

#define NUM_SEG 32
#define MUL 128
#define D 3
#define NUM_PATHS 64
#define ROW (NUM_SEG * MUL * D)   // 12288 floats per batch row
#define SEGF (MUL * D)            // 384 floats per full segment row
#define SEG_HF 192                // floats per segment in a u-half (64 u * 3)
#define PE_STRIDE 64              // schedule entries reserved per segment
#define M_PAD 12                  // m matrix padded 9 -> 12 floats (16B-aligned v4f)

typedef float v2f __attribute__((ext_vector_type(2)));
typedef float v4f __attribute__((ext_vector_type(4)));

// ---------------------------------------------------------------------------
// Setup kernel (one dispatch): block 0 builds the (b-independent) path
// schedule; blocks 1..B build per-(b,p) m matrices m[i][k] = sum_j x1*coeff.
// ---------------------------------------------------------------------------
__global__ __launch_bounds__(64) void ftp_setup(
    const float* __restrict__ x1, const float* __restrict__ coeff,
    const int* __restrict__ idx0, const int* __restrict__ idx1,
    const int* __restrict__ idx2,
    unsigned int* __restrict__ sched, float* __restrict__ m)
{
    const int tid = threadIdx.x;
    if (blockIdx.x == 0) {
        __shared__ int lcnt[NUM_SEG];
        __shared__ unsigned int lpe[NUM_SEG][PE_STRIDE];
        if (tid < NUM_SEG) lcnt[tid] = 0;
        __syncthreads();
        {
            const int p   = tid;                 // 64 threads == 64 paths
            const int s2  = idx2[p];
            const int pos = atomicAdd(&lcnt[s2], 1);
            lpe[s2][pos]  = (unsigned int)(idx0[p] | (p << 8));
        }
        __syncthreads();
        if (tid < NUM_SEG) sched[tid] = (unsigned int)lcnt[tid];
        for (int j = tid; j < NUM_SEG * PE_STRIDE; j += 64) {
            const int s = j / PE_STRIDE, t = j % PE_STRIDE;
            sched[NUM_SEG + j] = (t < lcnt[s]) ? lpe[s][t] : 0u;
        }
    } else {
        const int b = blockIdx.x - 1;
        const int p = tid;
        const float* xr = x1 + (size_t)b * (NUM_SEG * D) + idx1[p] * D;
        const float j0 = xr[0], j1 = xr[1], j2 = xr[2];
        const float* cf = coeff + p * 27;        // coeff[p][i][j][k]
        float mv[M_PAD];
        #pragma unroll
        for (int i = 0; i < D; ++i)
            #pragma unroll
            for (int k = 0; k < D; ++k)
                mv[i * 3 + k] = j0 * cf[i * 9 + k]
                              + j1 * cf[i * 9 + 3 + k]
                              + j2 * cf[i * 9 + 6 + k];
        mv[9] = 0.f; mv[10] = 0.f; mv[11] = 0.f;
        float* mp = m + ((size_t)b * NUM_PATHS + p) * M_PAD;
        *(v4f*)(mp)     = *(const v4f*)(mv);
        *(v4f*)(mp + 4) = *(const v4f*)(mv + 4);
        *(v4f*)(mp + 8) = *(const v4f*)(mv + 8);
    }
}

// ---------------------------------------------------------------------------
// Main kernel: no LDS, no barriers. Thread owns (seg-slot, u-quad); x0 read
// straight from global (block's half-row is L1/L2-resident across re-reads).
// ---------------------------------------------------------------------------
__global__ __launch_bounds__(256) void ftp_main(
    const float* __restrict__ x0, const unsigned int* __restrict__ sched,
    const float* __restrict__ m, float* __restrict__ out)
{
    const int bid = blockIdx.x;
    const int b   = bid >> 1;          // batch row
    const int h   = bid & 1;           // u-half: 0 -> u<64, 1 -> u>=64
    const int tid = threadIdx.x;
    const int qq  = tid & 15;          // u-quad: local u = 4*qq .. 4*qq+3
    const int ss  = tid >> 4;          // 16 concurrent segment slots

    const float* __restrict__ xb = x0  + (size_t)b * ROW + h * SEG_HF + qq * 12;
    float* __restrict__       ob = out + (size_t)b * ROW + h * SEG_HF + qq * 12;
    const float* __restrict__ mb = m + (size_t)b * NUM_PATHS * M_PAD;
    const unsigned int* __restrict__ pe = sched + NUM_SEG;

    const int n0 = (int)sched[ss];
    const int n1 = (int)sched[ss + 16];

    #pragma unroll
    for (int si = 0; si < 2; ++si) {
        const int s = ss + si * 16;
        const int n = si ? n1 : n0;
        const unsigned int* __restrict__ pes = pe + s * PE_STRIDE;
        float a00 = 0, a01 = 0, a02 = 0, a10 = 0, a11 = 0, a12 = 0;
        float a20 = 0, a21 = 0, a22 = 0, a30 = 0, a31 = 0, a32 = 0;
        for (int t = 0; t < n; ++t) {
            const unsigned e = pes[t];               // seg0 | p<<8 (16-lane uniform)
            const float* xs = xb + (e & 255u) * SEGF;
            const v4f X0 = *(const v4f*)(xs);        // u0k0 u0k1 u0k2 u1k0
            const v4f X1 = *(const v4f*)(xs + 4);    // u1k1 u1k2 u2k0 u2k1
            const v4f X2 = *(const v4f*)(xs + 8);    // u2k2 u3k0 u3k1 u3k2
            const float* mp = mb + (e >> 8) * M_PAD;
            const v4f MA = *(const v4f*)(mp);        // m00 m01 m02 m10
            const v4f MB = *(const v4f*)(mp + 4);    // m11 m12 m20 m21
            const float m22 = mp[8];
            // u0
            a00 += X0.x * MA.x + X0.y * MA.w + X0.z * MB.z;
            a01 += X0.x * MA.y + X0.y * MB.x + X0.z * MB.w;
            a02 += X0.x * MA.z + X0.y * MB.y + X0.z * m22;
            // u1
            a10 += X0.w * MA.x + X1.x * MA.w + X1.y * MB.z;
            a11 += X0.w * MA.y + X1.x * MB.x + X1.y * MB.w;
            a12 += X0.w * MA.z + X1.x * MB.y + X1.y * m22;
            // u2
            a20 += X1.z * MA.x + X1.w * MA.w + X2.x * MB.z;
            a21 += X1.z * MA.y + X1.w * MB.x + X2.x * MB.w;
            a22 += X1.z * MA.z + X1.w * MB.y + X2.x * m22;
            // u3
            a30 += X2.y * MA.x + X2.z * MA.w + X2.w * MB.z;
            a31 += X2.y * MA.y + X2.z * MB.x + X2.w * MB.w;
            a32 += X2.y * MA.z + X2.z * MB.y + X2.w * m22;
        }
        float* o = ob + s * SEGF;   // 16 lanes -> 768B contiguous per store trio
        v4f O0 = {a00, a01, a02, a10};
        v4f O1 = {a11, a12, a20, a21};
        v4f O2 = {a22, a30, a31, a32};
        *(v4f*)(o)     = O0;
        *(v4f*)(o + 4) = O1;
        *(v4f*)(o + 8) = O2;
    }
}

// ---------------------------------------------------------------------------
// Fallback: previous verified kernel (used only if ws_size is too small).
// ---------------------------------------------------------------------------
#define HALF_F4 1536

__global__ __launch_bounds__(256) void ftp_kernel(
    const float* __restrict__ x0, const float* __restrict__ x1,
    const float* __restrict__ coeff, const int* __restrict__ idx0,
    const int* __restrict__ idx1, const int* __restrict__ idx2,
    float* __restrict__ out)
{
    const int bid = blockIdx.x;
    const int b   = bid >> 1;
    const int h   = bid & 1;
    const int tid = threadIdx.x;

    __shared__ v4f   s_x0[HALF_F4];
    __shared__ float s_m[NUM_PATHS][9];
    __shared__ unsigned short s_pe[NUM_SEG][NUM_PATHS];
    __shared__ int   s_cnt[NUM_SEG];

    if (tid < NUM_SEG) s_cnt[tid] = 0;
    __syncthreads();

    const v4f* __restrict__ src = (const v4f*)(x0 + (size_t)b * ROW);
    #pragma unroll
    for (int j = 0; j < 6; ++j) {
        const int f     = j * 256 + tid;
        const int seg   = f / 48;
        const int inner = f - seg * 48;
        s_x0[f] = src[seg * 96 + h * 48 + inner];
    }

    if (tid < NUM_PATHS) {
        const int p  = tid;
        const int s0 = idx0[p];
        const int i1 = idx1[p];
        const int s2 = idx2[p];
        const int pos = atomicAdd(&s_cnt[s2], 1);
        s_pe[s2][pos] = (unsigned short)(s0 | (p << 8));

        const float* xr = x1 + (size_t)b * (NUM_SEG * D) + i1 * D;
        const float j0 = xr[0], j1 = xr[1], j2 = xr[2];
        const float* cf = coeff + p * 27;
        #pragma unroll
        for (int i = 0; i < D; ++i)
            #pragma unroll
            for (int k = 0; k < D; ++k)
                s_m[p][i * 3 + k] = j0 * cf[i * 9 + k]
                                  + j1 * cf[i * 9 + 3 + k]
                                  + j2 * cf[i * 9 + 6 + k];
    }
    __syncthreads();

    const int q  = tid & 31;
    const int ss = tid >> 5;
    float* __restrict__ ob = out + (size_t)b * ROW + h * SEG_HF + q * 6;
    const float* __restrict__ sx = (const float*)s_x0;

    #pragma unroll
    for (int si = 0; si < 4; ++si) {
        const int s = ss + si * 8;
        float a00 = 0, a01 = 0, a02 = 0, a10 = 0, a11 = 0, a12 = 0;
        const int n = s_cnt[s];
        for (int t = 0; t < n; ++t) {
            const int e = s_pe[s][t];
            const float* xs = sx + (e & 255) * SEG_HF + q * 6;
            const float u00 = xs[0], u01 = xs[1], u02 = xs[2];
            const float u10 = xs[3], u11 = xs[4], u12 = xs[5];
            const float* mm = s_m[e >> 8];
            a00 += u00 * mm[0] + u01 * mm[3] + u02 * mm[6];
            a01 += u00 * mm[1] + u01 * mm[4] + u02 * mm[7];
            a02 += u00 * mm[2] + u01 * mm[5] + u02 * mm[8];
            a10 += u10 * mm[0] + u11 * mm[3] + u12 * mm[6];
            a11 += u10 * mm[1] + u11 * mm[4] + u12 * mm[7];
            a12 += u10 * mm[2] + u11 * mm[5] + u12 * mm[8];
        }
        float* o = ob + s * SEGF;
        v2f O0 = {a00, a01}, O1 = {a02, a10}, O2 = {a11, a12};
        *(v2f*)(o + 0) = O0;
        *(v2f*)(o + 2) = O1;
        *(v2f*)(o + 4) = O2;
    }
}

extern "C" void kernel_launch(void* const* d_in, const int* in_sizes, int n_in,
                              void* d_out, int out_size, void* d_ws, size_t ws_size,
                              hipStream_t stream) {
    const float* x0    = (const float*)d_in[0];
    const float* x1    = (const float*)d_in[1];
    const float* coeff = (const float*)d_in[2];
    const int*   idx0  = (const int*)d_in[3];
    const int*   idx1  = (const int*)d_in[4];
    const int*   idx2  = (const int*)d_in[5];
    float* out = (float*)d_out;

    const int B = in_sizes[0] / ROW;

    const size_t schedBytes = (size_t)(NUM_SEG + NUM_SEG * PE_STRIDE) * sizeof(unsigned int);
    const size_t schedPad   = (schedBytes + 255) & ~(size_t)255;   // 256B-align m
    const size_t mBytes     = (size_t)B * NUM_PATHS * M_PAD * sizeof(float);

    if (ws_size >= schedPad + mBytes) {
        unsigned int* sched = (unsigned int*)d_ws;
        float*        m     = (float*)((char*)d_ws + schedPad);
        ftp_setup<<<B + 1, 64, 0, stream>>>(x1, coeff, idx0, idx1, idx2, sched, m);
        ftp_main<<<B * 2, 256, 0, stream>>>(x0, sched, m, out);
    } else {
        ftp_kernel<<<B * 2, 256, 0, stream>>>(x0, x1, coeff, idx0, idx1, idx2, out);
    }
}